// Round 5
// baseline (442.643 us; speedup 1.0000x reference)
//
#include <hip/hip_runtime.h>
#include <hip/hip_bf16.h>
#include <stdint.h>

// MoE gate: logits = r @ W^T + b ; soft = softmax(logits) ; hard = top8-renorm
// r: (32768, 2048) fp32, W: (64, 2048) fp32, b: (64,) fp32
// d_out: [hard (32768*64) | soft (32768*64)] fp32
//
// Precision: exact bf16^3 split of both operands, all 6 MFMA terms kept; D/L
// classes share one accumulator (merge error ~2^-27, invisible). Verified
// absmax 0.00195 vs 0.01625 thr across rounds.
//
// Round-8 theory: rounds 5-7 proved register-destination B prefetch is not
// robust at HIP source level (compiler sinks/remats it; VGPR=60 evidence).
// global_load_lds has NO dest register -> un-sinkable by construction. So:
// LDS-staged B (verified round-0 layout) but with the two round-0 defects
// fixed: (a) counted s_waitcnt vmcnt(2) + raw s_barrier instead of
// __syncthreads' vmcnt(0) drain — staging drains, A prefetch stays in
// flight; (b) no K-split — all 4 waves share one K-walk/one staged buffer,
// freeing ~96 VGPR. A prefetched distance-2 in 2 rotating reg slots.
// Paper roofline: HBM A-stream 16 KB/CU/kstep -> ~43 us floor; LDS and
// compute both ~2-4x under. Target 50-75 us.

#define D_DIM 2048
#define E_DIM 64
#define B_DIM 32768
#define TOPK 8
#define NKS 64   // k-steps of 32

typedef __bf16 bf16x8 __attribute__((ext_vector_type(8)));
typedef float f32x4 __attribute__((ext_vector_type(4)));

// ---- prep: W fp32 -> per-kstep fragment image (verified, unchanged) ----
// P[ks][split][2048 bf16] = 12 KB per kstep. Element (s, u*8+j) = split_s of
// W[e = u>>2][ks*32 + (u&3)*8 + j].
__global__ __launch_bounds__(256) void w_prep(const float* __restrict__ W,
                                              __bf16* __restrict__ P) {
    const int K = blockIdx.x;    // kstep 0..63
    const int u = threadIdx.x;   // slot 0..255
    const float* src = W + (size_t)(u >> 2) * D_DIM + K * 32 + (u & 3) * 8;
    __bf16* dst = P + (size_t)K * 6144 + u * 8;
    bf16x8 o1, o2, o3;
    #pragma unroll
    for (int j = 0; j < 8; ++j) {
        float x  = src[j];
        __bf16 h1 = (__bf16)x;
        float r1 = x - (float)h1;          // exact
        __bf16 h2 = (__bf16)r1;
        float r2 = r1 - (float)h2;         // exact
        o1[j] = h1; o2[j] = h2; o3[j] = (__bf16)r2;
    }
    *(bf16x8*)(dst)        = o1;
    *(bf16x8*)(dst + 2048) = o2;
    *(bf16x8*)(dst + 4096) = o3;
}

// async 16B global -> LDS (per lane; LDS dest = wave-uniform base + lane*16)
__device__ __forceinline__ void gload_lds16(const void* g, void* s) {
    __builtin_amdgcn_global_load_lds(
        (const __attribute__((address_space(1))) unsigned int*)g,
        (__attribute__((address_space(3))) unsigned int*)s,
        16, 0, 0);
}

__device__ __forceinline__ void fence_barrier() {
    __builtin_amdgcn_sched_barrier(0);
    __builtin_amdgcn_s_barrier();
    __builtin_amdgcn_sched_barrier(0);
}

// ---- main: 6-term split GEMM + fused softmax/top-8, LDS-staged pipeline ----
// Block = 256 thr = 4 waves, each wave 16 rows x 64 experts, shared K-walk.
// Grid = 512 blocks (64 rows each); 2 blocks/CU = 8 waves/CU.
__global__ __launch_bounds__(256, 2) void moe_gate(const float* __restrict__ r,
                                                   const __bf16* __restrict__ P,
                                                   const float* __restrict__ bias,
                                                   float* __restrict__ out) {
    __shared__ __bf16 bstage[2][3][2048];    // 24 KB double-buffered B image
    __shared__ float  lg[64][E_DIM + 1];     // 16.6 KB logits

    const int t    = threadIdx.x;
    const int wv   = t >> 6;
    const int lane = t & 63;
    const int lrow = lane & 15;
    const int quad = lane >> 4;
    const int row0 = blockIdx.x * 64;

    // staging: thread t moves 3x16 B per kstep, LDS image == P image (linear)
    const __bf16* Pt = P + t * 8;
    // A: row wv*16+lrow, k chunk quad*8
    const float* ra = r + (size_t)(row0 + wv * 16 + lrow) * D_DIM + quad * 8;
    // fragment offset within a split tile (verified layout)
    const int fo = quad * 8 + lrow * 32;

    f32x4 accM[4]  = {};   // h1*g1            (~1)
    f32x4 accDL[4] = {};   // 5 cross terms    (~2^-8)

    // A register slots, distance-2 rotation (slot reused every 2 ksteps)
    float4 Aa0, Aa1, Ab0, Ab1;

    // ---- prologue: stage ks=0, load A(0),A(1); drain staging only ----
    #pragma unroll
    for (int s = 0; s < 3; ++s)
        gload_lds16(Pt + s * 2048, &bstage[0][s][t * 8]);
    Aa0 = *(const float4*)(ra);
    Aa1 = *(const float4*)(ra + 4);
    Ab0 = *(const float4*)(ra + 32);
    Ab1 = *(const float4*)(ra + 36);
    asm volatile("s_waitcnt vmcnt(4)" ::: "memory");   // stage(0) done, A in flight
    fence_barrier();

// One k-step: stage next buf, read 12 frags of cur, split A slot, reload the
// slot for kk+2 (clamped), 24 MFMA, counted-drain + barrier.
#define ITER(CUR, NXT, A0_, A1_, kk) do {                                   \
        if ((kk) + 1 < NKS) {                                               \
            _Pragma("unroll")                                               \
            for (int s_ = 0; s_ < 3; ++s_)                                  \
                gload_lds16(Pt + (size_t)((kk) + 1) * 6144 + s_ * 2048,     \
                            &bstage[NXT][s_][t * 8]);                       \
        }                                                                   \
        bf16x8 Bf[3][4];                                                    \
        _Pragma("unroll")                                                   \
        for (int s_ = 0; s_ < 3; ++s_)                                      \
            _Pragma("unroll")                                               \
            for (int n_ = 0; n_ < 4; ++n_)                                  \
                Bf[s_][n_] = *(const bf16x8*)(&bstage[CUR][0][0] +          \
                                              s_ * 2048 + n_ * 512 + fo);   \
        float av_[8] = {A0_.x, A0_.y, A0_.z, A0_.w,                         \
                        A1_.x, A1_.y, A1_.z, A1_.w};                        \
        bf16x8 A1f, A2f, A3f;                                               \
        _Pragma("unroll")                                                   \
        for (int j_ = 0; j_ < 8; ++j_) {                                    \
            float x_  = av_[j_];                                            \
            __bf16 h1_ = (__bf16)x_;                                        \
            float r1_ = x_ - (float)h1_;                                    \
            __bf16 h2_ = (__bf16)r1_;                                       \
            float r2_ = r1_ - (float)h2_;                                   \
            A1f[j_] = h1_; A2f[j_] = h2_; A3f[j_] = (__bf16)r2_;            \
        }                                                                   \
        {   /* reload this slot for kk+2 (clamped: uniform vmcnt counts) */ \
            const int k2_ = ((kk) + 2 < NKS) ? (kk) + 2 : (kk);             \
            A0_ = *(const float4*)(ra + k2_ * 32);                          \
            A1_ = *(const float4*)(ra + k2_ * 32 + 4);                      \
        }                                                                   \
        _Pragma("unroll")                                                   \
        for (int n_ = 0; n_ < 4; ++n_)                                      \
            accM[n_]  = __builtin_amdgcn_mfma_f32_16x16x32_bf16(A1f, Bf[0][n_], accM[n_], 0, 0, 0);  \
        _Pragma("unroll")                                                   \
        for (int n_ = 0; n_ < 4; ++n_)                                      \
            accDL[n_] = __builtin_amdgcn_mfma_f32_16x16x32_bf16(A1f, Bf[1][n_], accDL[n_], 0, 0, 0); \
        _Pragma("unroll")                                                   \
        for (int n_ = 0; n_ < 4; ++n_)                                      \
            accDL[n_] = __builtin_amdgcn_mfma_f32_16x16x32_bf16(A2f, Bf[0][n_], accDL[n_], 0, 0, 0); \
        _Pragma("unroll")                                                   \
        for (int n_ = 0; n_ < 4; ++n_)                                      \
            accDL[n_] = __builtin_amdgcn_mfma_f32_16x16x32_bf16(A1f, Bf[2][n_], accDL[n_], 0, 0, 0); \
        _Pragma("unroll")                                                   \
        for (int n_ = 0; n_ < 4; ++n_)                                      \
            accDL[n_] = __builtin_amdgcn_mfma_f32_16x16x32_bf16(A2f, Bf[1][n_], accDL[n_], 0, 0, 0); \
        _Pragma("unroll")                                                   \
        for (int n_ = 0; n_ < 4; ++n_)                                      \
            accDL[n_] = __builtin_amdgcn_mfma_f32_16x16x32_bf16(A3f, Bf[0][n_], accDL[n_], 0, 0, 0); \
        /* drain staging (3 oldest); keep this iter's 2 A-loads in flight */ \
        asm volatile("s_waitcnt vmcnt(2)" ::: "memory");                    \
        fence_barrier();                                                    \
    } while (0)

    for (int ks = 0; ks < NKS; ks += 2) {
        ITER(0, 1, Aa0, Aa1, ks);
        ITER(1, 0, Ab0, Ab1, ks + 1);
    }
#undef ITER

    // C/D layout: col = lane&15, row = quad*4 + reg. Combine small-first.
    #pragma unroll
    for (int n = 0; n < 4; ++n) {
        int col = n * 16 + lrow;
        #pragma unroll
        for (int i = 0; i < 4; ++i)
            lg[wv * 16 + quad * 4 + i][col] = accM[n][i] + accDL[n][i];
    }
    __syncthreads();

    // softmax + top-8; wave per row, lane = expert. TEMPERATURE == 1.0.
    const float bcol = bias[lane];
    for (int rr = wv; rr < 64; rr += 4) {
        float logit = lg[rr][lane] + bcol;
        float mx = logit;
        #pragma unroll
        for (int s = 32; s >= 1; s >>= 1) mx = fmaxf(mx, __shfl_xor(mx, s));
        float ex = expf(logit - mx);
        float sm = ex;
        #pragma unroll
        for (int s = 32; s >= 1; s >>= 1) sm += __shfl_xor(sm, s);
        float soft = ex / sm;

        // top-8 on soft (monotone in logit); lowest-index tie-break = lax.top_k
        bool  sel    = false;
        float topsum = 0.0f;
        #pragma unroll
        for (int it = 0; it < TOPK; ++it) {
            float cand = sel ? -1.0f : soft;  // soft > 0 always
            float cm = cand;
            #pragma unroll
            for (int s = 32; s >= 1; s >>= 1) cm = fmaxf(cm, __shfl_xor(cm, s));
            unsigned long long ball = __ballot(cand == cm);
            int leader = __ffsll(ball) - 1;
            if (lane == leader) sel = true;
            topsum += cm;
        }
        float hard = sel ? soft / (topsum + 1e-9f) : 0.0f;

        size_t orow = (size_t)(row0 + rr) * E_DIM + lane;
        out[orow] = hard;
        out[(size_t)B_DIM * E_DIM + orow] = soft;
    }
}

extern "C" void kernel_launch(void* const* d_in, const int* in_sizes, int n_in,
                              void* d_out, int out_size, void* d_ws, size_t ws_size,
                              hipStream_t stream) {
    const float* r = (const float*)d_in[0];
    const float* W = (const float*)d_in[1];
    const float* b = (const float*)d_in[2];
    float* out = (float*)d_out;
    __bf16* P = (__bf16*)d_ws;   // 64 ksteps * 12 KB = 768 KB of ws

    w_prep<<<64, 256, 0, stream>>>(W, P);
    moe_gate<<<512, 256, 0, stream>>>(r, P, b, out);
}